// Round 3
// baseline (232.818 us; speedup 1.0000x reference)
//
#include <hip/hip_runtime.h>

#define NN 8000
#define NPAD 8064
#define NE 64000
#define INF 16
#define HH 128
#define MM 16
#define EDF 4
#define OUTF 4
#define NL 2
#define BN_EPS 1e-5f

typedef __attribute__((ext_vector_type(8))) short short8;
typedef __attribute__((ext_vector_type(4))) float f32x4;

static __device__ __forceinline__ unsigned short f2bf(float f) {
  unsigned u = __builtin_bit_cast(unsigned, f);
  u = (u + 0x7fffu + ((u >> 16) & 1u)) >> 16;
  return (unsigned short)u;
}
static __device__ __forceinline__ float bf2f(unsigned short s) {
  unsigned u = ((unsigned)s) << 16;
  return __builtin_bit_cast(float, u);
}

// counts: in-degree (float, for mean) and out-degree (int, for sort)
__global__ void deg_count_k(const int* __restrict__ ei, float* __restrict__ deg,
                            int* __restrict__ cnt) {
  int e = blockIdx.x * blockDim.x + threadIdx.x;
  if (e < NE) {
    atomicAdd(&deg[ei[NE + e]], 1.0f);
    atomicAdd(&cnt[ei[e]], 1);
  }
}

// exclusive prefix sum of cnt[0..NN) -> base[0..NN]
__global__ __launch_bounds__(1024) void scan_k(const int* __restrict__ cnt,
                                               int* __restrict__ base) {
  __shared__ int part[1024];
  int t = threadIdx.x;
  int v[8], s = 0;
#pragma unroll
  for (int j = 0; j < 8; ++j) {
    int idx = t * 8 + j;
    v[j] = (idx < NN) ? cnt[idx] : 0;
    s += v[j];
  }
  part[t] = s;
  __syncthreads();
  for (int off = 1; off < 1024; off <<= 1) {
    int x = (t >= off) ? part[t - off] : 0;
    __syncthreads();
    part[t] += x;
    __syncthreads();
  }
  int ex = (t > 0) ? part[t - 1] : 0;
#pragma unroll
  for (int j = 0; j < 8; ++j) {
    int idx = t * 8 + j;
    if (idx < NN) base[idx] = ex;
    ex += v[j];
  }
  if (t == 1023) base[NN] = part[1023];
}

__global__ void scatter_k(const int* __restrict__ ei, const int* __restrict__ base,
                          int* __restrict__ cur, int* __restrict__ sorted) {
  int e = blockIdx.x * blockDim.x + threadIdx.x;
  if (e < NE) {
    int src = ei[e];
    int p = base[src] + atomicAdd(&cur[src], 1);
    sorted[p] = e;
  }
}

__global__ void in_proj_k(const float* __restrict__ x, const float* __restrict__ W,
                          const float* __restrict__ b, float* __restrict__ h,
                          unsigned short* __restrict__ hb) {
  int n = blockIdx.x;
  int t = threadIdx.x;  // 0..127
  __shared__ float sx[INF];
  if (t < INF) sx[t] = x[n * INF + t];
  __syncthreads();
  float acc = b[t];
#pragma unroll
  for (int i = 0; i < INF; ++i) acc = fmaf(sx[i], W[i * HH + t], acc);
  h[n * HH + t] = acc;
  hb[n * HH + t] = f2bf(acc);
}

// Bp[c][h] = bf16(W2[k, h*16+m]) with c = k*16+m
__global__ void bp_build_k(const float* __restrict__ W2, unsigned short* __restrict__ Bp) {
  int idx = blockIdx.x * 256 + threadIdx.x;
  if (idx >= HH * MM * HH) return;
  int c = idx >> 7;
  int hdim = idx & 127;
  int k = c >> 4, m = c & 15;
  Bp[idx] = f2bf(W2[k * (HH * MM) + hdim * MM + m]);
}

// Qn[NPAD x 2048] (bf16) = hb @ Bp^T
__global__ __launch_bounds__(256) void gemm_qn_mfma(const unsigned short* __restrict__ hb,
                                                    const unsigned short* __restrict__ Bp,
                                                    unsigned short* __restrict__ Qn) {
  __shared__ unsigned short sA[16384];
  __shared__ unsigned short sB[16384];
  int tid = threadIdx.x;
  int bm = blockIdx.y, bn = blockIdx.x;

  const float4* gA = (const float4*)(hb + (size_t)bm * 128 * 128);
  const float4* gB = (const float4*)(Bp + (size_t)bn * 128 * 128);
#pragma unroll
  for (int r = 0; r < 8; ++r) {
    int s = r * 256 + tid;
    int d = s ^ ((s >> 4) & 7);
    float4 va = gA[s];
    float4 vb = gB[s];
    *(float4*)&sA[d * 8] = va;
    *(float4*)&sB[d * 8] = vb;
  }
  __syncthreads();

  int wid = tid >> 6, lane = tid & 63;
  int wr = (wid >> 1) * 64;
  int wc = (wid & 1) * 64;
  int l15 = lane & 15, l4 = lane >> 4;

  f32x4 acc[4][4] = {};
#pragma unroll
  for (int ks = 0; ks < 4; ++ks) {
    short8 af[4], bfr[4];
    int kb = ks * 4 + l4;
#pragma unroll
    for (int mr = 0; mr < 4; ++mr) {
      int r = wr + mr * 16 + l15;
      af[mr] = *(const short8*)&sA[(r * 16 + (kb ^ (r & 7))) * 8];
    }
#pragma unroll
    for (int nc = 0; nc < 4; ++nc) {
      int r = wc + nc * 16 + l15;
      bfr[nc] = *(const short8*)&sB[(r * 16 + (kb ^ (r & 7))) * 8];
    }
#pragma unroll
    for (int mr = 0; mr < 4; ++mr)
#pragma unroll
      for (int nc = 0; nc < 4; ++nc)
        acc[mr][nc] = __builtin_amdgcn_mfma_f32_16x16x32_bf16(af[mr], bfr[nc], acc[mr][nc], 0, 0, 0);
  }

#pragma unroll
  for (int mr = 0; mr < 4; ++mr) {
    int r0 = bm * 128 + wr + mr * 16 + l4 * 4;
#pragma unroll
    for (int nc = 0; nc < 4; ++nc) {
      int c0 = bn * 128 + wc + nc * 16 + l15;
#pragma unroll
      for (int j = 0; j < 4; ++j)
        Qn[(size_t)(r0 + j) * (HH * MM) + c0] = f2bf(acc[mr][nc][j]);
    }
  }
}

// B2[n,m] = sum_h h[n,h] * b2[h*16+m] ; 16 nodes per block
__global__ __launch_bounds__(256) void b2_term_k(const float* __restrict__ h,
                                                 const float* __restrict__ b2,
                                                 float* __restrict__ B2) {
  __shared__ float sb2[HH * MM];
  __shared__ float shr[16][HH];
  int tid = threadIdx.x;
  for (int i = tid; i < HH * MM; i += 256) sb2[i] = b2[i];
  int n0 = blockIdx.x * 16;
  for (int i = tid; i < 16 * HH; i += 256) shr[i >> 7][i & 127] = h[(n0 + (i >> 7)) * HH + (i & 127)];
  __syncthreads();
  int ni = tid >> 4, m = tid & 15;
  float s = 0.f;
#pragma unroll
  for (int k = 0; k < HH; ++k) s = fmaf(shr[ni][k], sb2[k * MM + m], s);
  B2[(n0 + ni) * MM + m] = s;
}

// one wave per SRC node: load Qn[src] once, loop its edges
__global__ __launch_bounds__(256) void edge_msg_grouped(const int* __restrict__ ei,
                                                        const float* __restrict__ ea,
                                                        const int* __restrict__ base,
                                                        const int* __restrict__ sorted,
                                                        const float* __restrict__ W1,
                                                        const float* __restrict__ b1,
                                                        const unsigned short* __restrict__ Qn,
                                                        const float* __restrict__ B2,
                                                        float* __restrict__ agg) {
  __shared__ float sW1[EDF * HH];
  __shared__ float sb1[HH];
  int tid = threadIdx.x;
  for (int i = tid; i < EDF * HH; i += 256) sW1[i] = W1[i];
  if (tid < HH) sb1[tid] = b1[tid];
  __syncthreads();
  int src = blockIdx.x * 4 + (tid >> 6);
  int lane = tid & 63;
  int kg = lane >> 2, mg = lane & 3;

  int i0 = base[src], i1 = base[src + 1];
  if (i0 == i1) return;

  // Qn[src] row: lane reads 8B at offset lane*8 per j-step (fully coalesced)
  float qf[8][4];
  const unsigned short* q = Qn + (size_t)src * (HH * MM);
#pragma unroll
  for (int j = 0; j < 8; ++j) {
    ushort4 qv = *(const ushort4*)&q[(j * 16 + kg) * MM + mg * 4];
    qf[j][0] = bf2f(qv.x);
    qf[j][1] = bf2f(qv.y);
    qf[j][2] = bf2f(qv.z);
    qf[j][3] = bf2f(qv.w);
  }
  float4 b2v = *(const float4*)&B2[(size_t)src * MM + mg * 4];

  for (int i = i0; i < i1; ++i) {
    int e = sorted[i];
    int dst = ei[NE + e];
    float4 a = *(const float4*)&ea[e * 4];
    float acc0 = 0.f, acc1 = 0.f, acc2 = 0.f, acc3 = 0.f;
#pragma unroll
    for (int j = 0; j < 8; ++j) {
      int k = j * 16 + kg;
      float r = fmaf(a.w, sW1[3 * HH + k],
                 fmaf(a.z, sW1[2 * HH + k], fmaf(a.y, sW1[HH + k], fmaf(a.x, sW1[k], sb1[k]))));
      r = fmaxf(r, 0.f);
      acc0 = fmaf(r, qf[j][0], acc0);
      acc1 = fmaf(r, qf[j][1], acc1);
      acc2 = fmaf(r, qf[j][2], acc2);
      acc3 = fmaf(r, qf[j][3], acc3);
    }
#pragma unroll
    for (int msk = 4; msk <= 32; msk <<= 1) {
      acc0 += __shfl_xor(acc0, msk);
      acc1 += __shfl_xor(acc1, msk);
      acc2 += __shfl_xor(acc2, msk);
      acc3 += __shfl_xor(acc3, msk);
    }
    if (kg == 0) {
      float* ar = agg + (size_t)dst * MM + mg * 4;
      atomicAdd(ar + 0, acc0 + b2v.x);
      atomicAdd(ar + 1, acc1 + b2v.y);
      atomicAdd(ar + 2, acc2 + b2v.z);
      atomicAdd(ar + 3, acc3 + b2v.w);
    }
  }
}

// 16 nodes/block: x_msg = agg/deg + h@rootW + cbias ; hpre = h + x_msg@msgW + msgb
// fused BN partial sums
__global__ __launch_bounds__(256) void node_update_k(const float* __restrict__ h,
                                                     const float* __restrict__ agg,
                                                     const float* __restrict__ deg,
                                                     const float* __restrict__ rootW,
                                                     const float* __restrict__ cbias,
                                                     const float* __restrict__ msgW,
                                                     const float* __restrict__ msgb,
                                                     float* __restrict__ hpre,
                                                     float* __restrict__ sums) {
  __shared__ float srw[HH * MM];
  __shared__ float smw[MM * HH];
  __shared__ float sh[16][HH];
  __shared__ float xm[16][MM];
  __shared__ float scb[MM];
  __shared__ float smb[HH];
  __shared__ float red[256];
  int tid = threadIdx.x;
  int n0 = blockIdx.x * 16;
  for (int i = tid; i < HH * MM; i += 256) {
    srw[i] = rootW[i];
    smw[i] = msgW[i];
  }
  if (tid < MM) scb[tid] = cbias[tid];
  if (tid < HH) smb[tid] = msgb[tid];
  for (int i = tid; i < 16 * HH; i += 256) sh[i >> 7][i & 127] = h[(n0 + (i >> 7)) * HH + (i & 127)];
  __syncthreads();

  {
    int ni = tid >> 4, m = tid & 15;
    float s = 0.f;
#pragma unroll
    for (int k = 0; k < HH; ++k) s = fmaf(sh[ni][k], srw[k * MM + m], s);
    int n = n0 + ni;
    xm[ni][m] = agg[n * MM + m] / fmaxf(deg[n], 1.0f) + s + scb[m];
  }
  __syncthreads();

  int t = tid & 127;
  float lsum = 0.f, lss = 0.f;
#pragma unroll
  for (int pass = 0; pass < 8; ++pass) {
    int ni = pass * 2 + (tid >> 7);
    float hp = sh[ni][t] + smb[t];
#pragma unroll
    for (int m = 0; m < MM; ++m) hp = fmaf(xm[ni][m], smw[m * HH + t], hp);
    hpre[(n0 + ni) * HH + t] = hp;
    lsum += hp;
    lss = fmaf(hp, hp, lss);
  }
  red[tid] = lsum;
  __syncthreads();
  if (tid < 128) {
    atomicAdd(&sums[t], red[tid] + red[tid + 128]);
  }
  __syncthreads();
  red[tid] = lss;
  __syncthreads();
  if (tid < 128) {
    atomicAdd(&sums[HH + t], red[tid] + red[tid + 128]);
  }
}

// fused bn_final + normalize + relu ; emits f32 h and bf16 hb
__global__ void norm_relu_k(const float* __restrict__ hp, const float* __restrict__ sums,
                            const float* __restrict__ gamma, const float* __restrict__ beta,
                            float* __restrict__ h, unsigned short* __restrict__ hb) {
  int i4 = blockIdx.x * 256 + threadIdx.x;
  if (i4 >= NN * HH / 4) return;
  int c0 = (i4 * 4) & 127;
  float4 v = ((const float4*)hp)[i4];
  float4 o;
  ushort4 ob;
  float inv = 1.0f / NN;
#pragma unroll
  for (int j = 0; j < 4; ++j) {
    int c = c0 + j;
    float mu = sums[c] * inv;
    float var = sums[HH + c] * inv - mu * mu;
    float s = gamma[c] * rsqrtf(var + BN_EPS);
    float val = (&v.x)[j];
    val = fmaxf(0.f, (val - mu) * s + beta[c]);
    (&o.x)[j] = val;
    (&ob.x)[j] = f2bf(val);
  }
  ((float4*)h)[i4] = o;
  ((ushort4*)hb)[i4] = ob;
}

__global__ void out_proj_k(const float* __restrict__ h, const float* __restrict__ W,
                           const float* __restrict__ b, float* __restrict__ out) {
  int n = blockIdx.x * 4 + (threadIdx.x >> 6);
  int lane = threadIdx.x & 63;
  if (n >= NN) return;
  float acc0 = 0.f, acc1 = 0.f, acc2 = 0.f, acc3 = 0.f;
#pragma unroll
  for (int rep = 0; rep < 2; ++rep) {
    int hh = lane + rep * 64;
    float hv = h[n * HH + hh];
    acc0 = fmaf(hv, W[hh * OUTF + 0], acc0);
    acc1 = fmaf(hv, W[hh * OUTF + 1], acc1);
    acc2 = fmaf(hv, W[hh * OUTF + 2], acc2);
    acc3 = fmaf(hv, W[hh * OUTF + 3], acc3);
  }
#pragma unroll
  for (int s = 32; s > 0; s >>= 1) {
    acc0 += __shfl_down(acc0, s);
    acc1 += __shfl_down(acc1, s);
    acc2 += __shfl_down(acc2, s);
    acc3 += __shfl_down(acc3, s);
  }
  if (lane == 0) {
    out[n * OUTF + 0] = acc0 + b[0];
    out[n * OUTF + 1] = acc1 + b[1];
    out[n * OUTF + 2] = acc2 + b[2];
    out[n * OUTF + 3] = acc3 + b[3];
  }
}

extern "C" void kernel_launch(void* const* d_in, const int* in_sizes, int n_in,
                              void* d_out, int out_size, void* d_ws, size_t ws_size,
                              hipStream_t stream) {
  (void)in_sizes; (void)n_in; (void)out_size; (void)ws_size;
  const float* x    = (const float*)d_in[0];
  const int* ei     = (const int*)d_in[1];
  const float* ea   = (const float*)d_in[2];
  const float* inW  = (const float*)d_in[3];
  const float* inb  = (const float*)d_in[4];
  const float* cW1  = (const float*)d_in[5];
  const float* cb1  = (const float*)d_in[6];
  const float* cW2  = (const float*)d_in[7];
  const float* cb2  = (const float*)d_in[8];
  const float* rW   = (const float*)d_in[9];
  const float* cbias= (const float*)d_in[10];
  const float* gam  = (const float*)d_in[11];
  const float* bet  = (const float*)d_in[12];
  const float* mW   = (const float*)d_in[13];
  const float* mb   = (const float*)d_in[14];
  const float* oW   = (const float*)d_in[15];
  const float* ob   = (const float*)d_in[16];
  float* out = (float*)d_out;

  float* ws = (float*)d_ws;
  size_t off = 0;
  float* deg  = ws + off; off += 8192;
  float* h    = ws + off; off += (size_t)NPAD * HH;
  float* hpre = ws + off; off += (size_t)NPAD * HH;
  float* agg  = ws + off; off += (size_t)NN * MM;
  float* B2   = ws + off; off += (size_t)NN * MM;
  float* sums = ws + off; off += 256;
  unsigned short* Bp = (unsigned short*)(ws + off); off += (size_t)HH * MM * HH / 2;
  unsigned short* hb = (unsigned short*)(ws + off); off += (size_t)NPAD * HH / 2;
  unsigned short* Qn = (unsigned short*)(ws + off); off += (size_t)NPAD * HH * MM / 2;
  int* cnt    = (int*)(ws + off); off += 8192;
  int* cur    = (int*)(ws + off); off += 8192;
  int* basev  = (int*)(ws + off); off += 8192;
  int* sorted = (int*)(ws + off); off += NE;

  hipMemsetAsync(deg, 0, NN * sizeof(float), stream);
  hipMemsetAsync(cnt, 0, NN * sizeof(int), stream);
  hipMemsetAsync(cur, 0, NN * sizeof(int), stream);
  hipMemsetAsync(hb + (size_t)NN * HH, 0, (size_t)(NPAD - NN) * HH * sizeof(unsigned short), stream);
  deg_count_k<<<(NE + 255) / 256, 256, 0, stream>>>(ei, deg, cnt);
  scan_k<<<1, 1024, 0, stream>>>(cnt, basev);
  scatter_k<<<(NE + 255) / 256, 256, 0, stream>>>(ei, basev, cur, sorted);
  in_proj_k<<<NN, HH, 0, stream>>>(x, inW, inb, h, hb);

  for (int l = 0; l < NL; ++l) {
    bp_build_k<<<(HH * MM * HH + 255) / 256, 256, 0, stream>>>(cW2 + (size_t)l * HH * HH * MM, Bp);
    dim3 gg(HH * MM / 128, NPAD / 128);
    gemm_qn_mfma<<<gg, 256, 0, stream>>>(hb, Bp, Qn);
    b2_term_k<<<NN / 16, 256, 0, stream>>>(h, cb2 + (size_t)l * HH * MM, B2);
    hipMemsetAsync(agg, 0, (size_t)NN * MM * sizeof(float), stream);
    edge_msg_grouped<<<NN / 4, 256, 0, stream>>>(ei, ea, basev, sorted,
                                                 cW1 + (size_t)l * EDF * HH,
                                                 cb1 + (size_t)l * HH, Qn, B2, agg);
    hipMemsetAsync(sums, 0, 2 * HH * sizeof(float), stream);
    node_update_k<<<NN / 16, 256, 0, stream>>>(h, agg, deg, rW + (size_t)l * HH * MM,
                                               cbias + (size_t)l * MM, mW + (size_t)l * MM * HH,
                                               mb + (size_t)l * HH, hpre, sums);
    norm_relu_k<<<(NN * HH / 4 + 255) / 256, 256, 0, stream>>>(hpre, sums, gam + (size_t)l * HH,
                                                               bet + (size_t)l * HH, h, hb);
  }
  out_proj_k<<<NN / 4, 256, 0, stream>>>(h, oW, ob, out);
}

// Round 4
// 195.631 us; speedup vs baseline: 1.1901x; 1.1901x over previous
//
#include <hip/hip_runtime.h>

#define NN 8000
#define NPAD 8064
#define NE 64000
#define INF 16
#define HH 128
#define MM 16
#define EDF 4
#define OUTF 4
#define NL 2
#define BN_EPS 1e-5f

typedef __attribute__((ext_vector_type(8))) short short8;
typedef __attribute__((ext_vector_type(4))) float f32x4;

static __device__ __forceinline__ unsigned short f2bf(float f) {
  unsigned u = __builtin_bit_cast(unsigned, f);
  u = (u + 0x7fffu + ((u >> 16) & 1u)) >> 16;
  return (unsigned short)u;
}

// LDS row permutation: ensures B-frag reads (fixed m, k = l4*8+j) are conflict-free
static __device__ __forceinline__ int qperm(int k) {
  return ((k >> 3) & 3) | ((k & 7) << 2) | (k & 0x60);
}

__global__ void deg_count_k(const int* __restrict__ ei, float* __restrict__ deg,
                            int* __restrict__ cnt) {
  int e = blockIdx.x * blockDim.x + threadIdx.x;
  if (e < NE) {
    atomicAdd(&deg[ei[NE + e]], 1.0f);
    atomicAdd(&cnt[ei[e]], 1);
  }
}

// exclusive prefix sum of cnt[0..NN) -> base[0..NN]
__global__ __launch_bounds__(1024) void scan_k(const int* __restrict__ cnt,
                                               int* __restrict__ base) {
  __shared__ int part[1024];
  int t = threadIdx.x;
  int v[8], s = 0;
#pragma unroll
  for (int j = 0; j < 8; ++j) {
    int idx = t * 8 + j;
    v[j] = (idx < NN) ? cnt[idx] : 0;
    s += v[j];
  }
  part[t] = s;
  __syncthreads();
  for (int off = 1; off < 1024; off <<= 1) {
    int x = (t >= off) ? part[t - off] : 0;
    __syncthreads();
    part[t] += x;
    __syncthreads();
  }
  int ex = (t > 0) ? part[t - 1] : 0;
#pragma unroll
  for (int j = 0; j < 8; ++j) {
    int idx = t * 8 + j;
    if (idx < NN) base[idx] = ex;
    ex += v[j];
  }
  if (t == 1023) base[NN] = part[1023];
}

// sort edges by src; pre-gather edge_attr and dst into sorted order
__global__ void scatter_k(const int* __restrict__ ei, const float* __restrict__ ea,
                          const int* __restrict__ base, int* __restrict__ cur,
                          float* __restrict__ ea_s, int* __restrict__ dst_s) {
  int e = blockIdx.x * blockDim.x + threadIdx.x;
  if (e < NE) {
    int src = ei[e];
    int p = base[src] + atomicAdd(&cur[src], 1);
    *(float4*)&ea_s[p * 4] = *(const float4*)&ea[e * 4];
    dst_s[p] = ei[NE + e];
  }
}

__global__ void in_proj_k(const float* __restrict__ x, const float* __restrict__ W,
                          const float* __restrict__ b, float* __restrict__ h,
                          unsigned short* __restrict__ hb) {
  int n = blockIdx.x;
  int t = threadIdx.x;  // 0..127
  __shared__ float sx[INF];
  if (t < INF) sx[t] = x[n * INF + t];
  __syncthreads();
  float acc = b[t];
#pragma unroll
  for (int i = 0; i < INF; ++i) acc = fmaf(sx[i], W[i * HH + t], acc);
  h[n * HH + t] = acc;
  hb[n * HH + t] = f2bf(acc);
}

// Bp[c][h] = bf16(W2[k, h*16+m]) with c = k*16+m
__global__ void bp_build_k(const float* __restrict__ W2, unsigned short* __restrict__ Bp) {
  int idx = blockIdx.x * 256 + threadIdx.x;
  if (idx >= HH * MM * HH) return;
  int c = idx >> 7;
  int hdim = idx & 127;
  int k = c >> 4, m = c & 15;
  Bp[idx] = f2bf(W2[k * (HH * MM) + hdim * MM + m]);
}

// Qn[NPAD x 2048] (bf16) = hb @ Bp^T
__global__ __launch_bounds__(256) void gemm_qn_mfma(const unsigned short* __restrict__ hb,
                                                    const unsigned short* __restrict__ Bp,
                                                    unsigned short* __restrict__ Qn) {
  __shared__ unsigned short sA[16384];
  __shared__ unsigned short sB[16384];
  int tid = threadIdx.x;
  int bm = blockIdx.y, bn = blockIdx.x;

  const float4* gA = (const float4*)(hb + (size_t)bm * 128 * 128);
  const float4* gB = (const float4*)(Bp + (size_t)bn * 128 * 128);
#pragma unroll
  for (int r = 0; r < 8; ++r) {
    int s = r * 256 + tid;
    int d = s ^ ((s >> 4) & 7);
    float4 va = gA[s];
    float4 vb = gB[s];
    *(float4*)&sA[d * 8] = va;
    *(float4*)&sB[d * 8] = vb;
  }
  __syncthreads();

  int wid = tid >> 6, lane = tid & 63;
  int wr = (wid >> 1) * 64;
  int wc = (wid & 1) * 64;
  int l15 = lane & 15, l4 = lane >> 4;

  f32x4 acc[4][4] = {};
#pragma unroll
  for (int ks = 0; ks < 4; ++ks) {
    short8 af[4], bfr[4];
    int kb = ks * 4 + l4;
#pragma unroll
    for (int mr = 0; mr < 4; ++mr) {
      int r = wr + mr * 16 + l15;
      af[mr] = *(const short8*)&sA[(r * 16 + (kb ^ (r & 7))) * 8];
    }
#pragma unroll
    for (int nc = 0; nc < 4; ++nc) {
      int r = wc + nc * 16 + l15;
      bfr[nc] = *(const short8*)&sB[(r * 16 + (kb ^ (r & 7))) * 8];
    }
#pragma unroll
    for (int mr = 0; mr < 4; ++mr)
#pragma unroll
      for (int nc = 0; nc < 4; ++nc)
        acc[mr][nc] = __builtin_amdgcn_mfma_f32_16x16x32_bf16(af[mr], bfr[nc], acc[mr][nc], 0, 0, 0);
  }

#pragma unroll
  for (int mr = 0; mr < 4; ++mr) {
    int r0 = bm * 128 + wr + mr * 16 + l4 * 4;
#pragma unroll
    for (int nc = 0; nc < 4; ++nc) {
      int c0 = bn * 128 + wc + nc * 16 + l15;
#pragma unroll
      for (int j = 0; j < 4; ++j)
        Qn[(size_t)(r0 + j) * (HH * MM) + c0] = f2bf(acc[mr][nc][j]);
    }
  }
}

// B2[n,m] = sum_h h[n,h] * b2[h*16+m] ; 16 nodes per block
__global__ __launch_bounds__(256) void b2_term_k(const float* __restrict__ h,
                                                 const float* __restrict__ b2,
                                                 float* __restrict__ B2) {
  __shared__ float sb2[HH * MM];
  __shared__ float shr[16][HH];
  int tid = threadIdx.x;
  for (int i = tid; i < HH * MM; i += 256) sb2[i] = b2[i];
  int n0 = blockIdx.x * 16;
  for (int i = tid; i < 16 * HH; i += 256) shr[i >> 7][i & 127] = h[(n0 + (i >> 7)) * HH + (i & 127)];
  __syncthreads();
  int ni = tid >> 4, m = tid & 15;
  float s = 0.f;
#pragma unroll
  for (int k = 0; k < HH; ++k) s = fmaf(shr[ni][k], sb2[k * MM + m], s);
  B2[(n0 + ni) * MM + m] = s;
}

// One wave per src node: P[d x 16] = relu1[d x 128] @ Qn[n][128 x 16] via MFMA.
// relu1 computed in-register (once per (edge,k)); Qn staged in LDS with qperm rows.
__global__ __launch_bounds__(256) void contract_k(const float* __restrict__ ea_s,
                                                  const int* __restrict__ dst_s,
                                                  const int* __restrict__ base,
                                                  const float* __restrict__ W1,
                                                  const float* __restrict__ b1,
                                                  const unsigned short* __restrict__ Qn,
                                                  const float* __restrict__ B2,
                                                  float* __restrict__ agg) {
  __shared__ float sW1[EDF * HH];
  __shared__ float sb1[HH];
  __shared__ unsigned short sQ[4][HH * MM];  // 4 waves x 4KB, row k at qperm(k)*16
  int tid = threadIdx.x;
  for (int i = tid; i < EDF * HH; i += 256) sW1[i] = W1[i];
  if (tid < HH) sb1[tid] = b1[tid];
  __syncthreads();

  int wid = tid >> 6, lane = tid & 63;
  int n = blockIdx.x * 4 + wid;
  int l15 = lane & 15, l4 = lane >> 4;
  int i0 = base[n], i1 = base[n + 1];
  if (i0 == i1) return;

  // stage Qn[n] (4KB): lane handles rows {lane, lane+64}, 32B each, permuted dest
  {
    const unsigned short* q = Qn + (size_t)n * (HH * MM);
#pragma unroll
    for (int rr = 0; rr < 2; ++rr) {
      int k = lane + rr * 64;
      uint4 lo = *(const uint4*)(q + k * 16);
      uint4 hi = *(const uint4*)(q + k * 16 + 8);
      int p = qperm(k) * 16;
      *(uint4*)&sQ[wid][p] = lo;
      *(uint4*)&sQ[wid][p + 8] = hi;
    }
  }
  float b2v = B2[(size_t)n * MM + l15];
  __builtin_amdgcn_s_waitcnt(0);  // wave-local LDS writes complete (lgkm)

  for (int t0 = i0; t0 < i1; t0 += 16) {
    int row = t0 + l15;
    bool valid = row < i1;
    float4 eav = valid ? *(const float4*)&ea_s[(size_t)row * 4]
                       : make_float4(0.f, 0.f, 0.f, 0.f);
    f32x4 acc = {0.f, 0.f, 0.f, 0.f};
#pragma unroll
    for (int ks = 0; ks < 4; ++ks) {
      short8 a, b;
#pragma unroll
      for (int j = 0; j < 8; ++j) {
        int k = ks * 32 + l4 * 8 + j;
        float r = fmaf(eav.w, sW1[3 * HH + k],
                   fmaf(eav.z, sW1[2 * HH + k],
                     fmaf(eav.y, sW1[HH + k], fmaf(eav.x, sW1[k], sb1[k]))));
        r = fmaxf(r, 0.f);
        a[j] = valid ? (short)f2bf(r) : (short)0;
        b[j] = (short)sQ[wid][qperm(k) * 16 + l15];
      }
      acc = __builtin_amdgcn_mfma_f32_16x16x32_bf16(a, b, acc, 0, 0, 0);
    }
    // C: row = l4*4 + j (edge), col = l15 (m)
#pragma unroll
    for (int j = 0; j < 4; ++j) {
      int r = t0 + l4 * 4 + j;
      if (r < i1) {
        int dst = dst_s[r];
        atomicAdd(&agg[(size_t)dst * MM + l15], acc[j] + b2v);
      }
    }
  }
}

// 16 nodes/block: x_msg = agg/deg + h@rootW + cbias ; hpre = h + x_msg@msgW + msgb
// fused BN partial sums
__global__ __launch_bounds__(256) void node_update_k(const float* __restrict__ h,
                                                     const float* __restrict__ agg,
                                                     const float* __restrict__ deg,
                                                     const float* __restrict__ rootW,
                                                     const float* __restrict__ cbias,
                                                     const float* __restrict__ msgW,
                                                     const float* __restrict__ msgb,
                                                     float* __restrict__ hpre,
                                                     float* __restrict__ sums) {
  __shared__ float srw[HH * MM];
  __shared__ float smw[MM * HH];
  __shared__ float sh[16][HH];
  __shared__ float xm[16][MM];
  __shared__ float scb[MM];
  __shared__ float smb[HH];
  __shared__ float red[256];
  int tid = threadIdx.x;
  int n0 = blockIdx.x * 16;
  for (int i = tid; i < HH * MM; i += 256) {
    srw[i] = rootW[i];
    smw[i] = msgW[i];
  }
  if (tid < MM) scb[tid] = cbias[tid];
  if (tid < HH) smb[tid] = msgb[tid];
  for (int i = tid; i < 16 * HH; i += 256) sh[i >> 7][i & 127] = h[(n0 + (i >> 7)) * HH + (i & 127)];
  __syncthreads();

  {
    int ni = tid >> 4, m = tid & 15;
    float s = 0.f;
#pragma unroll
    for (int k = 0; k < HH; ++k) s = fmaf(sh[ni][k], srw[k * MM + m], s);
    int n = n0 + ni;
    xm[ni][m] = agg[n * MM + m] / fmaxf(deg[n], 1.0f) + s + scb[m];
  }
  __syncthreads();

  int t = tid & 127;
  float lsum = 0.f, lss = 0.f;
#pragma unroll
  for (int pass = 0; pass < 8; ++pass) {
    int ni = pass * 2 + (tid >> 7);
    float hp = sh[ni][t] + smb[t];
#pragma unroll
    for (int m = 0; m < MM; ++m) hp = fmaf(xm[ni][m], smw[m * HH + t], hp);
    hpre[(n0 + ni) * HH + t] = hp;
    lsum += hp;
    lss = fmaf(hp, hp, lss);
  }
  red[tid] = lsum;
  __syncthreads();
  if (tid < 128) atomicAdd(&sums[t], red[tid] + red[tid + 128]);
  __syncthreads();
  red[tid] = lss;
  __syncthreads();
  if (tid < 128) atomicAdd(&sums[HH + t], red[tid] + red[tid + 128]);
}

// fused bn_final + normalize + relu ; emits f32 h and bf16 hb
__global__ void norm_relu_k(const float* __restrict__ hp, const float* __restrict__ sums,
                            const float* __restrict__ gamma, const float* __restrict__ beta,
                            float* __restrict__ h, unsigned short* __restrict__ hb) {
  int i4 = blockIdx.x * 256 + threadIdx.x;
  if (i4 >= NN * HH / 4) return;
  int c0 = (i4 * 4) & 127;
  float4 v = ((const float4*)hp)[i4];
  float4 o;
  ushort4 ob;
  float inv = 1.0f / NN;
#pragma unroll
  for (int j = 0; j < 4; ++j) {
    int c = c0 + j;
    float mu = sums[c] * inv;
    float var = sums[HH + c] * inv - mu * mu;
    float s = gamma[c] * rsqrtf(var + BN_EPS);
    float val = (&v.x)[j];
    val = fmaxf(0.f, (val - mu) * s + beta[c]);
    (&o.x)[j] = val;
    (&ob.x)[j] = f2bf(val);
  }
  ((float4*)h)[i4] = o;
  ((ushort4*)hb)[i4] = ob;
}

__global__ void out_proj_k(const float* __restrict__ h, const float* __restrict__ W,
                           const float* __restrict__ b, float* __restrict__ out) {
  int n = blockIdx.x * 4 + (threadIdx.x >> 6);
  int lane = threadIdx.x & 63;
  if (n >= NN) return;
  float acc0 = 0.f, acc1 = 0.f, acc2 = 0.f, acc3 = 0.f;
#pragma unroll
  for (int rep = 0; rep < 2; ++rep) {
    int hh = lane + rep * 64;
    float hv = h[n * HH + hh];
    acc0 = fmaf(hv, W[hh * OUTF + 0], acc0);
    acc1 = fmaf(hv, W[hh * OUTF + 1], acc1);
    acc2 = fmaf(hv, W[hh * OUTF + 2], acc2);
    acc3 = fmaf(hv, W[hh * OUTF + 3], acc3);
  }
#pragma unroll
  for (int s = 32; s > 0; s >>= 1) {
    acc0 += __shfl_down(acc0, s);
    acc1 += __shfl_down(acc1, s);
    acc2 += __shfl_down(acc2, s);
    acc3 += __shfl_down(acc3, s);
  }
  if (lane == 0) {
    out[n * OUTF + 0] = acc0 + b[0];
    out[n * OUTF + 1] = acc1 + b[1];
    out[n * OUTF + 2] = acc2 + b[2];
    out[n * OUTF + 3] = acc3 + b[3];
  }
}

extern "C" void kernel_launch(void* const* d_in, const int* in_sizes, int n_in,
                              void* d_out, int out_size, void* d_ws, size_t ws_size,
                              hipStream_t stream) {
  (void)in_sizes; (void)n_in; (void)out_size; (void)ws_size;
  const float* x    = (const float*)d_in[0];
  const int* ei     = (const int*)d_in[1];
  const float* ea   = (const float*)d_in[2];
  const float* inW  = (const float*)d_in[3];
  const float* inb  = (const float*)d_in[4];
  const float* cW1  = (const float*)d_in[5];
  const float* cb1  = (const float*)d_in[6];
  const float* cW2  = (const float*)d_in[7];
  const float* cb2  = (const float*)d_in[8];
  const float* rW   = (const float*)d_in[9];
  const float* cbias= (const float*)d_in[10];
  const float* gam  = (const float*)d_in[11];
  const float* bet  = (const float*)d_in[12];
  const float* mW   = (const float*)d_in[13];
  const float* mb   = (const float*)d_in[14];
  const float* oW   = (const float*)d_in[15];
  const float* ob   = (const float*)d_in[16];
  float* out = (float*)d_out;

  float* ws = (float*)d_ws;
  size_t off = 0;
  float* deg  = ws + off; off += 8192;
  float* h    = ws + off; off += (size_t)NPAD * HH;
  float* hpre = ws + off; off += (size_t)NPAD * HH;
  float* agg  = ws + off; off += (size_t)NN * MM;
  float* B2   = ws + off; off += (size_t)NN * MM;
  float* sums = ws + off; off += 256;
  unsigned short* Bp = (unsigned short*)(ws + off); off += (size_t)HH * MM * HH / 2;
  unsigned short* hb = (unsigned short*)(ws + off); off += (size_t)NPAD * HH / 2;
  unsigned short* Qn = (unsigned short*)(ws + off); off += (size_t)NPAD * HH * MM / 2;
  int* cnt    = (int*)(ws + off); off += 8192;
  int* cur    = (int*)(ws + off); off += 8192;
  int* basev  = (int*)(ws + off); off += 8192;
  float* ea_s = ws + off; off += (size_t)NE * 4;
  int* dst_s  = (int*)(ws + off); off += NE;

  hipMemsetAsync(deg, 0, NN * sizeof(float), stream);
  hipMemsetAsync(cnt, 0, NN * sizeof(int), stream);
  hipMemsetAsync(cur, 0, NN * sizeof(int), stream);
  hipMemsetAsync(hb + (size_t)NN * HH, 0, (size_t)(NPAD - NN) * HH * sizeof(unsigned short), stream);
  deg_count_k<<<(NE + 255) / 256, 256, 0, stream>>>(ei, deg, cnt);
  scan_k<<<1, 1024, 0, stream>>>(cnt, basev);
  scatter_k<<<(NE + 255) / 256, 256, 0, stream>>>(ei, ea, basev, cur, ea_s, dst_s);
  in_proj_k<<<NN, HH, 0, stream>>>(x, inW, inb, h, hb);

  for (int l = 0; l < NL; ++l) {
    bp_build_k<<<(HH * MM * HH + 255) / 256, 256, 0, stream>>>(cW2 + (size_t)l * HH * HH * MM, Bp);
    dim3 gg(HH * MM / 128, NPAD / 128);
    gemm_qn_mfma<<<gg, 256, 0, stream>>>(hb, Bp, Qn);
    b2_term_k<<<NN / 16, 256, 0, stream>>>(h, cb2 + (size_t)l * HH * MM, B2);
    hipMemsetAsync(agg, 0, (size_t)NN * MM * sizeof(float), stream);
    contract_k<<<NN / 4, 256, 0, stream>>>(ea_s, dst_s, basev, cW1 + (size_t)l * EDF * HH,
                                           cb1 + (size_t)l * HH, Qn, B2, agg);
    hipMemsetAsync(sums, 0, 2 * HH * sizeof(float), stream);
    node_update_k<<<NN / 16, 256, 0, stream>>>(h, agg, deg, rW + (size_t)l * HH * MM,
                                               cbias + (size_t)l * MM, mW + (size_t)l * MM * HH,
                                               mb + (size_t)l * HH, hpre, sums);
    norm_relu_k<<<(NN * HH / 4 + 255) / 256, 256, 0, stream>>>(hpre, sums, gam + (size_t)l * HH,
                                                               bet + (size_t)l * HH, h, hb);
  }
  out_proj_k<<<NN / 4, 256, 0, stream>>>(h, oW, ob, out);
}

// Round 5
// 174.472 us; speedup vs baseline: 1.3344x; 1.1213x over previous
//
#include <hip/hip_runtime.h>

#define NN 8000
#define NPAD 8064
#define NE 64000
#define INF 16
#define HH 128
#define MM 16
#define EDF 4
#define OUTF 4
#define NL 2
#define BN_EPS 1e-5f

typedef __attribute__((ext_vector_type(8))) short short8;
typedef __attribute__((ext_vector_type(4))) float f32x4;

static __device__ __forceinline__ unsigned short f2bf(float f) {
  unsigned u = __builtin_bit_cast(unsigned, f);
  u = (u + 0x7fffu + ((u >> 16) & 1u)) >> 16;
  return (unsigned short)u;
}

// LDS row permutation for contract_k B-frag conflict avoidance
static __device__ __forceinline__ int qperm(int k) {
  return ((k >> 3) & 3) | ((k & 7) << 2) | (k & 0x60);
}

__global__ void deg_count_k(const int* __restrict__ ei, float* __restrict__ deg,
                            int* __restrict__ cnt) {
  int e = blockIdx.x * blockDim.x + threadIdx.x;
  if (e < NE) {
    atomicAdd(&deg[ei[NE + e]], 1.0f);
    atomicAdd(&cnt[ei[e]], 1);
  }
}

__global__ __launch_bounds__(1024) void scan_k(const int* __restrict__ cnt,
                                               int* __restrict__ base) {
  __shared__ int part[1024];
  int t = threadIdx.x;
  int v[8], s = 0;
#pragma unroll
  for (int j = 0; j < 8; ++j) {
    int idx = t * 8 + j;
    v[j] = (idx < NN) ? cnt[idx] : 0;
    s += v[j];
  }
  part[t] = s;
  __syncthreads();
  for (int off = 1; off < 1024; off <<= 1) {
    int x = (t >= off) ? part[t - off] : 0;
    __syncthreads();
    part[t] += x;
    __syncthreads();
  }
  int ex = (t > 0) ? part[t - 1] : 0;
#pragma unroll
  for (int j = 0; j < 8; ++j) {
    int idx = t * 8 + j;
    if (idx < NN) base[idx] = ex;
    ex += v[j];
  }
  if (t == 1023) base[NN] = part[1023];
}

__global__ void scatter_k(const int* __restrict__ ei, const float* __restrict__ ea,
                          const int* __restrict__ base, int* __restrict__ cur,
                          float* __restrict__ ea_s, int* __restrict__ dst_s) {
  int e = blockIdx.x * blockDim.x + threadIdx.x;
  if (e < NE) {
    int src = ei[e];
    int p = base[src] + atomicAdd(&cur[src], 1);
    *(float4*)&ea_s[p * 4] = *(const float4*)&ea[e * 4];
    dst_s[p] = ei[NE + e];
  }
}

__global__ void in_proj_k(const float* __restrict__ x, const float* __restrict__ W,
                          const float* __restrict__ b, float* __restrict__ h,
                          unsigned short* __restrict__ hb) {
  int n = blockIdx.x;
  int t = threadIdx.x;  // 0..127
  __shared__ float sx[INF];
  if (t < INF) sx[t] = x[n * INF + t];
  __syncthreads();
  float acc = b[t];
#pragma unroll
  for (int i = 0; i < INF; ++i) acc = fmaf(sx[i], W[i * HH + t], acc);
  h[n * HH + t] = acc;
  hb[n * HH + t] = f2bf(acc);
}

// Fused: (optional BN+relu of previous layer on A-stage) + W2 transpose-stage +
// Qn GEMM + B2 mini-GEMM (bn==16) + agg/sums_out zeroing.
// grid (17, 63): bn<16 -> Qn cols [bn*128,+128); bn==16 -> B2.
__global__ __launch_bounds__(256) void gemm_fused(
    const unsigned short* __restrict__ hb, const float* __restrict__ hpre,
    const float* __restrict__ bnsums, const float* __restrict__ gamma,
    const float* __restrict__ beta, int bn_mode,
    const float* __restrict__ W2, const float* __restrict__ b2,
    unsigned short* __restrict__ Qn, float* __restrict__ B2,
    float* __restrict__ agg, float* __restrict__ sums_out) {
  __shared__ unsigned short sA[16384];
  __shared__ unsigned short sB[16384];
  int tid = threadIdx.x;
  int bm = blockIdx.y, bn = blockIdx.x;
  int r0 = bm * 128;

  // distributed zeroing of agg (32000 uint4) and sums_out (64 uint4)
  {
    int b = bm * 17 + bn;
    uint4 z = make_uint4(0, 0, 0, 0);
    if (tid < 30) {
      int idx = b * 30 + tid;
      if (idx < 32000) ((uint4*)agg)[idx] = z;
    }
    if (b == 0 && tid >= 32 && tid < 96) ((uint4*)sums_out)[tid - 32] = z;
  }

  // ---- A staging: 128 rows x 128 ch, bf16, XOR-swizzled 16B slots ----
  if (bn_mode == 0) {
#pragma unroll
    for (int rr = 0; rr < 8; ++rr) {
      int s = rr * 256 + tid;
      int row = s >> 4, k8 = s & 15;
      int n = r0 + row;
      uint4 v = make_uint4(0, 0, 0, 0);
      if (n < NN) v = *(const uint4*)&hb[(size_t)n * HH + k8 * 8];
      *(uint4*)&sA[(row * 16 + (k8 ^ (row & 7))) * 8] = v;
    }
  } else {
    int k8 = tid & 15;
    int c0 = k8 * 8;
    float scl[8], shf[8];
#pragma unroll
    for (int j = 0; j < 8; ++j) {
      int c = c0 + j;
      float mu = bnsums[c] * (1.0f / NN);
      float var = bnsums[HH + c] * (1.0f / NN) - mu * mu;
      float sc = gamma[c] * rsqrtf(var + BN_EPS);
      scl[j] = sc;
      shf[j] = beta[c] - mu * sc;
    }
#pragma unroll
    for (int rr = 0; rr < 8; ++rr) {
      int s = rr * 256 + tid;
      int row = s >> 4;
      int n = r0 + row;
      short8 o = {0, 0, 0, 0, 0, 0, 0, 0};
      if (n < NN) {
        float4 v0 = *(const float4*)&hpre[(size_t)n * HH + c0];
        float4 v1 = *(const float4*)&hpre[(size_t)n * HH + c0 + 4];
#pragma unroll
        for (int j = 0; j < 4; ++j) {
          float a = fmaxf(0.f, fmaf((&v0.x)[j], scl[j], shf[j]));
          float bb = fmaxf(0.f, fmaf((&v1.x)[j], scl[4 + j], shf[4 + j]));
          o[j] = (short)f2bf(a);
          o[4 + j] = (short)f2bf(bb);
        }
      }
      *(short8*)&sA[(row * 16 + (k8 ^ (row & 7))) * 8] = o;
    }
  }

  // ---- B staging ----
  if (bn < 16) {
    // transpose W2 rows k=bn*8..+8: element W2[k][h*16+m] -> crow=(k-bn*8)*16+m, col h
    const float* w2blk = W2 + (size_t)bn * 8 * 2048;
#pragma unroll
    for (int it = 0; it < 16; ++it) {
      int idx4 = it * 256 + tid;       // 4096 float4 = 16384 f32
      int kk = idx4 >> 9;
      int rem4 = idx4 & 511;
      float4 v = *(const float4*)&w2blk[(size_t)kk * 2048 + rem4 * 4];
      int h = (rem4 * 4) >> 4;
      int m0 = (rem4 * 4) & 15;
#pragma unroll
      for (int j = 0; j < 4; ++j) {
        int crow = kk * 16 + m0 + j;
        sB[(crow * 16 + ((h >> 3) ^ (crow & 7))) * 8 + (h & 7)] = f2bf((&v.x)[j]);
      }
    }
  } else {
    // B2 block: sB rows 0..15 = b2 reshaped [h][m] transposed; rest zero
    uint4 z = make_uint4(0, 0, 0, 0);
#pragma unroll
    for (int it = 0; it < 8; ++it) *(uint4*)&sB[(it * 256 + tid) * 8] = z;
    __syncthreads();
#pragma unroll
    for (int it = 0; it < 2; ++it) {
      int f0 = (it * 256 + tid) * 4;
      float4 v = *(const float4*)&b2[f0];
#pragma unroll
      for (int j = 0; j < 4; ++j) {
        int f = f0 + j;
        int h = f >> 4, m = f & 15;
        sB[(m * 16 + ((h >> 3) ^ (m & 7))) * 8 + (h & 7)] = f2bf((&v.x)[j]);
      }
    }
  }
  __syncthreads();

  int wid = tid >> 6, lane = tid & 63;
  int wr = (wid >> 1) * 64;
  int wc = (wid & 1) * 64;
  int l15 = lane & 15, l4 = lane >> 4;

  f32x4 acc[4][4] = {};
#pragma unroll
  for (int ks = 0; ks < 4; ++ks) {
    short8 af[4], bfr[4];
    int kb = ks * 4 + l4;
#pragma unroll
    for (int mr = 0; mr < 4; ++mr) {
      int r = wr + mr * 16 + l15;
      af[mr] = *(const short8*)&sA[(r * 16 + (kb ^ (r & 7))) * 8];
    }
#pragma unroll
    for (int nc = 0; nc < 4; ++nc) {
      int r = wc + nc * 16 + l15;
      bfr[nc] = *(const short8*)&sB[(r * 16 + (kb ^ (r & 7))) * 8];
    }
#pragma unroll
    for (int mr = 0; mr < 4; ++mr)
#pragma unroll
      for (int nc = 0; nc < 4; ++nc)
        acc[mr][nc] = __builtin_amdgcn_mfma_f32_16x16x32_bf16(af[mr], bfr[nc], acc[mr][nc], 0, 0, 0);
  }

  if (bn < 16) {
#pragma unroll
    for (int mr = 0; mr < 4; ++mr) {
      int rr0 = r0 + wr + mr * 16 + l4 * 4;
#pragma unroll
      for (int nc = 0; nc < 4; ++nc) {
        int c0 = bn * 128 + wc + nc * 16 + l15;
#pragma unroll
        for (int j = 0; j < 4; ++j)
          Qn[(size_t)(rr0 + j) * (HH * MM) + c0] = f2bf(acc[mr][nc][j]);
      }
    }
  } else if (wc == 0) {
#pragma unroll
    for (int mr = 0; mr < 4; ++mr) {
      int rr0 = r0 + wr + mr * 16 + l4 * 4;
#pragma unroll
      for (int j = 0; j < 4; ++j)
        B2[(size_t)(rr0 + j) * MM + l15] = acc[mr][0][j];
    }
  }
}

// One wave per src node: P[d x 16] = relu1[d x 128] @ Qn[n][128 x 16] via MFMA.
__global__ __launch_bounds__(256) void contract_k(const float* __restrict__ ea_s,
                                                  const int* __restrict__ dst_s,
                                                  const int* __restrict__ base,
                                                  const float* __restrict__ W1,
                                                  const float* __restrict__ b1,
                                                  const unsigned short* __restrict__ Qn,
                                                  const float* __restrict__ B2,
                                                  float* __restrict__ agg) {
  __shared__ float sW1[EDF * HH];
  __shared__ float sb1[HH];
  __shared__ unsigned short sQ[4][HH * MM];
  int tid = threadIdx.x;
  for (int i = tid; i < EDF * HH; i += 256) sW1[i] = W1[i];
  if (tid < HH) sb1[tid] = b1[tid];
  __syncthreads();

  int wid = tid >> 6, lane = tid & 63;
  int n = blockIdx.x * 4 + wid;
  int l15 = lane & 15, l4 = lane >> 4;
  int i0 = base[n], i1 = base[n + 1];
  if (i0 == i1) return;

  {
    const unsigned short* q = Qn + (size_t)n * (HH * MM);
#pragma unroll
    for (int rr = 0; rr < 2; ++rr) {
      int k = lane + rr * 64;
      uint4 lo = *(const uint4*)(q + k * 16);
      uint4 hi = *(const uint4*)(q + k * 16 + 8);
      int p = qperm(k) * 16;
      *(uint4*)&sQ[wid][p] = lo;
      *(uint4*)&sQ[wid][p + 8] = hi;
    }
  }
  float b2v = B2[(size_t)n * MM + l15];
  __builtin_amdgcn_s_waitcnt(0);

  for (int t0 = i0; t0 < i1; t0 += 16) {
    int row = t0 + l15;
    bool valid = row < i1;
    float4 eav = valid ? *(const float4*)&ea_s[(size_t)row * 4]
                       : make_float4(0.f, 0.f, 0.f, 0.f);
    f32x4 acc = {0.f, 0.f, 0.f, 0.f};
#pragma unroll
    for (int ks = 0; ks < 4; ++ks) {
      short8 a, b;
#pragma unroll
      for (int j = 0; j < 8; ++j) {
        int k = ks * 32 + l4 * 8 + j;
        float r = fmaf(eav.w, sW1[3 * HH + k],
                   fmaf(eav.z, sW1[2 * HH + k],
                     fmaf(eav.y, sW1[HH + k], fmaf(eav.x, sW1[k], sb1[k]))));
        r = fmaxf(r, 0.f);
        a[j] = valid ? (short)f2bf(r) : (short)0;
        b[j] = (short)sQ[wid][qperm(k) * 16 + l15];
      }
      acc = __builtin_amdgcn_mfma_f32_16x16x32_bf16(a, b, acc, 0, 0, 0);
    }
#pragma unroll
    for (int j = 0; j < 4; ++j) {
      int r = t0 + l4 * 4 + j;
      if (r < i1) {
        int dst = dst_s[r];
        atomicAdd(&agg[(size_t)dst * MM + l15], acc[j] + b2v);
      }
    }
  }
}

// 16 nodes/block; optional inline BN+relu of previous layer's hpre to form h.
__global__ __launch_bounds__(256) void node_update_k(
    const float* __restrict__ hplain, const float* __restrict__ hsrc_pre,
    const float* __restrict__ bnsums, const float* __restrict__ gamma,
    const float* __restrict__ beta, int bn_mode,
    const float* __restrict__ agg, const float* __restrict__ deg,
    const float* __restrict__ rootW, const float* __restrict__ cbias,
    const float* __restrict__ msgW, const float* __restrict__ msgb,
    float* __restrict__ hpre, float* __restrict__ sums) {
  __shared__ float srw[HH * MM];
  __shared__ float smw[MM * HH];
  __shared__ float sh[16][HH];
  __shared__ float xm[16][MM];
  __shared__ float scb[MM];
  __shared__ float smb[HH];
  __shared__ float red[256];
  __shared__ float sscl[HH], sshf[HH];
  int tid = threadIdx.x;
  int n0 = blockIdx.x * 16;
  for (int i = tid; i < HH * MM; i += 256) {
    srw[i] = rootW[i];
    smw[i] = msgW[i];
  }
  if (tid < MM) scb[tid] = cbias[tid];
  if (tid < HH) smb[tid] = msgb[tid];
  if (bn_mode && tid < HH) {
    float mu = bnsums[tid] * (1.0f / NN);
    float var = bnsums[HH + tid] * (1.0f / NN) - mu * mu;
    float sc = gamma[tid] * rsqrtf(var + BN_EPS);
    sscl[tid] = sc;
    sshf[tid] = beta[tid] - mu * sc;
  }
  __syncthreads();
  for (int i = tid; i < 16 * HH; i += 256) {
    int ni = i >> 7, c = i & 127;
    if (bn_mode) {
      float v = hsrc_pre[(size_t)(n0 + ni) * HH + c];
      sh[ni][c] = fmaxf(0.f, fmaf(v, sscl[c], sshf[c]));
    } else {
      sh[ni][c] = hplain[(size_t)(n0 + ni) * HH + c];
    }
  }
  __syncthreads();

  {
    int ni = tid >> 4, m = tid & 15;
    float s = 0.f;
#pragma unroll
    for (int k = 0; k < HH; ++k) s = fmaf(sh[ni][k], srw[k * MM + m], s);
    int n = n0 + ni;
    xm[ni][m] = agg[n * MM + m] / fmaxf(deg[n], 1.0f) + s + scb[m];
  }
  __syncthreads();

  int t = tid & 127;
  float lsum = 0.f, lss = 0.f;
#pragma unroll
  for (int pass = 0; pass < 8; ++pass) {
    int ni = pass * 2 + (tid >> 7);
    float hp = sh[ni][t] + smb[t];
#pragma unroll
    for (int m = 0; m < MM; ++m) hp = fmaf(xm[ni][m], smw[m * HH + t], hp);
    hpre[(size_t)(n0 + ni) * HH + t] = hp;
    lsum += hp;
    lss = fmaf(hp, hp, lss);
  }
  red[tid] = lsum;
  __syncthreads();
  if (tid < 128) atomicAdd(&sums[t], red[tid] + red[tid + 128]);
  __syncthreads();
  red[tid] = lss;
  __syncthreads();
  if (tid < 128) atomicAdd(&sums[HH + t], red[tid] + red[tid + 128]);
}

// out = BN_relu(hpre1) @ W + b, BN inline
__global__ void out_proj_k(const float* __restrict__ hpre,
                           const float* __restrict__ bnsums,
                           const float* __restrict__ gamma,
                           const float* __restrict__ beta,
                           const float* __restrict__ W, const float* __restrict__ b,
                           float* __restrict__ out) {
  __shared__ float sscl[HH], sshf[HH];
  int tid = threadIdx.x;
  if (tid < HH) {
    float mu = bnsums[tid] * (1.0f / NN);
    float var = bnsums[HH + tid] * (1.0f / NN) - mu * mu;
    float sc = gamma[tid] * rsqrtf(var + BN_EPS);
    sscl[tid] = sc;
    sshf[tid] = beta[tid] - mu * sc;
  }
  __syncthreads();
  int n = blockIdx.x * 4 + (tid >> 6);
  int lane = tid & 63;
  if (n >= NN) return;
  float acc0 = 0.f, acc1 = 0.f, acc2 = 0.f, acc3 = 0.f;
#pragma unroll
  for (int rep = 0; rep < 2; ++rep) {
    int hh = lane + rep * 64;
    float hv = fmaxf(0.f, fmaf(hpre[(size_t)n * HH + hh], sscl[hh], sshf[hh]));
    acc0 = fmaf(hv, W[hh * OUTF + 0], acc0);
    acc1 = fmaf(hv, W[hh * OUTF + 1], acc1);
    acc2 = fmaf(hv, W[hh * OUTF + 2], acc2);
    acc3 = fmaf(hv, W[hh * OUTF + 3], acc3);
  }
#pragma unroll
  for (int s = 32; s > 0; s >>= 1) {
    acc0 += __shfl_down(acc0, s);
    acc1 += __shfl_down(acc1, s);
    acc2 += __shfl_down(acc2, s);
    acc3 += __shfl_down(acc3, s);
  }
  if (lane == 0) {
    out[n * OUTF + 0] = acc0 + b[0];
    out[n * OUTF + 1] = acc1 + b[1];
    out[n * OUTF + 2] = acc2 + b[2];
    out[n * OUTF + 3] = acc3 + b[3];
  }
}

extern "C" void kernel_launch(void* const* d_in, const int* in_sizes, int n_in,
                              void* d_out, int out_size, void* d_ws, size_t ws_size,
                              hipStream_t stream) {
  (void)in_sizes; (void)n_in; (void)out_size; (void)ws_size;
  const float* x    = (const float*)d_in[0];
  const int* ei     = (const int*)d_in[1];
  const float* ea   = (const float*)d_in[2];
  const float* inW  = (const float*)d_in[3];
  const float* inb  = (const float*)d_in[4];
  const float* cW1  = (const float*)d_in[5];
  const float* cb1  = (const float*)d_in[6];
  const float* cW2  = (const float*)d_in[7];
  const float* cb2  = (const float*)d_in[8];
  const float* rW   = (const float*)d_in[9];
  const float* cbias= (const float*)d_in[10];
  const float* gam  = (const float*)d_in[11];
  const float* bet  = (const float*)d_in[12];
  const float* mW   = (const float*)d_in[13];
  const float* mb   = (const float*)d_in[14];
  const float* oW   = (const float*)d_in[15];
  const float* ob   = (const float*)d_in[16];
  float* out = (float*)d_out;

  float* ws = (float*)d_ws;
  size_t off = 0;
  float* deg   = ws + off; off += 8192;   // deg/cnt/cur contiguous for 1 memset
  int* cnt     = (int*)(ws + off); off += 8192;
  int* cur     = (int*)(ws + off); off += 8192;
  float* h     = ws + off; off += (size_t)NPAD * HH;
  float* hpre0 = ws + off; off += (size_t)NPAD * HH;
  float* hpre1 = ws + off; off += (size_t)NPAD * HH;
  float* agg   = ws + off; off += (size_t)NN * MM;
  float* B2    = ws + off; off += (size_t)NPAD * MM;
  float* sums0 = ws + off; off += 256;
  float* sums1 = ws + off; off += 256;
  unsigned short* hb = (unsigned short*)(ws + off); off += (size_t)NPAD * HH / 2;
  unsigned short* Qn = (unsigned short*)(ws + off); off += (size_t)NPAD * HH * MM / 2;
  int* basev   = (int*)(ws + off); off += 8192;
  float* ea_s  = ws + off; off += (size_t)NE * 4;
  int* dst_s   = (int*)(ws + off); off += NE;

  hipMemsetAsync(deg, 0, 3 * 8192 * sizeof(float), stream);
  deg_count_k<<<(NE + 255) / 256, 256, 0, stream>>>(ei, deg, cnt);
  scan_k<<<1, 1024, 0, stream>>>(cnt, basev);
  scatter_k<<<(NE + 255) / 256, 256, 0, stream>>>(ei, ea, basev, cur, ea_s, dst_s);
  in_proj_k<<<NN, HH, 0, stream>>>(x, inW, inb, h, hb);

  dim3 gg(17, 63);
  // ---- layer 0 ----
  gemm_fused<<<gg, 256, 0, stream>>>(hb, hpre0, sums0, gam, bet, 0,
                                     cW2, cb2, Qn, B2, agg, sums0);
  contract_k<<<NN / 4, 256, 0, stream>>>(ea_s, dst_s, basev, cW1, cb1, Qn, B2, agg);
  node_update_k<<<NN / 16, 256, 0, stream>>>(h, hpre0, sums0, gam, bet, 0,
                                             agg, deg, rW, cbias, mW, mb,
                                             hpre0, sums0);
  // ---- layer 1 ----
  gemm_fused<<<gg, 256, 0, stream>>>(hb, hpre0, sums0, gam, bet, 1,
                                     cW2 + (size_t)HH * HH * MM, cb2 + HH * MM,
                                     Qn, B2, agg, sums1);
  contract_k<<<NN / 4, 256, 0, stream>>>(ea_s, dst_s, basev, cW1 + EDF * HH,
                                         cb1 + HH, Qn, B2, agg);
  node_update_k<<<NN / 16, 256, 0, stream>>>(h, hpre0, sums0, gam, bet, 1,
                                             agg, deg, rW + HH * MM, cbias + MM,
                                             mW + MM * HH, mb + HH,
                                             hpre1, sums1);
  out_proj_k<<<NN / 4, 256, 0, stream>>>(hpre1, sums1, gam + HH, bet + HH,
                                         oW, ob, out);
}